// Round 7
// baseline (888.314 us; speedup 1.0000x reference)
//
#include <hip/hip_runtime.h>

#define NN 100000
#define NU 50000
#define NI 50000
#define NE 1600000
#define NSLICE 3
#define SLICEW 33334

// LDS histogram geometry
#define HSLICE 4
#define HCHUNK 64
#define HSW 25600          // counters per slice; 4*25600 >= NN
#define HEPC (NE/HCHUNK)   // edges per chunk = 25000

typedef unsigned short u16;
typedef unsigned int u32;

typedef __attribute__((ext_vector_type(8))) short s16x8;
typedef __attribute__((ext_vector_type(4))) float f32x4;
typedef __attribute__((ext_vector_type(4))) unsigned short us4;

__device__ __forceinline__ float bf2f(u16 u){
  union { u32 i; float f; } v; v.i = ((u32)u) << 16; return v.f;
}
__device__ __forceinline__ u16 f2bf(float f){
  union { float f; u32 i; } v; v.f = f;
  u32 u = v.i;
  return (u16)((u + 0x7FFFu + ((u >> 16) & 1u)) >> 16);
}
__device__ __forceinline__ u32 pack2(float lo, float hi){
  return (u32)f2bf(lo) | ((u32)f2bf(hi) << 16);
}
__device__ __forceinline__ float lrelu(float x){ return x > 0.f ? x : 0.01f * x; }
__device__ __forceinline__ float san(float v){
  union { float f; u32 i; } u; u.f = v;
  return ((u.i & 0x7F800000u) == 0x7F800000u) ? 0.f : v;
}

// ---------------------------------------------------------------------------
// Weight pre-transpose (fp32 in -> bf16 transposed out)
// ---------------------------------------------------------------------------
__global__ __launch_bounds__(256) void transpose_weights(
    const float* __restrict__ trans_w, const float* __restrict__ wsw,
    const float* __restrict__ desw, const float* __restrict__ outw,
    u16* __restrict__ Ttw, u16* __restrict__ Tw, u16* __restrict__ Td, u16* __restrict__ To)
{
  __shared__ u16 L[128][136];
  int b = blockIdx.x, t = threadIdx.x;
  const float* src; u16* dst; int stride;
  if (b < 2)      { src = trans_w + b*16384;        dst = Ttw + b*128;          stride = 256; }
  else if (b < 5) { int i = b-2; src = wsw  + i*16384; dst = Tw + i*16384;      stride = 128; }
  else if (b < 8) { int i = b-5; src = desw + i*16384; dst = Td + i*16384;      stride = 128; }
  else            { int i = (b-8)>>1, h = (b-8)&1;
                    src = outw + i*32768 + h*16384;    dst = To + i*32768 + h*128; stride = 256; }
  #pragma unroll
  for (int p = 0; p < 8; p++){
    int fi = (p*256 + t)*8;
    int r = fi >> 7, c = fi & 127;
    f32x4 v0 = *(const f32x4*)(src + r*128 + c);
    f32x4 v1 = *(const f32x4*)(src + r*128 + c + 4);
    L[c+0][r] = f2bf(san(v0.x)); L[c+1][r] = f2bf(san(v0.y));
    L[c+2][r] = f2bf(san(v0.z)); L[c+3][r] = f2bf(san(v0.w));
    L[c+4][r] = f2bf(san(v1.x)); L[c+5][r] = f2bf(san(v1.y));
    L[c+6][r] = f2bf(san(v1.z)); L[c+7][r] = f2bf(san(v1.w));
  }
  __syncthreads();
  #pragma unroll
  for (int p = 0; p < 8; p++){
    int fi = (p*256 + t)*8;
    int n = fi >> 7, k = fi & 127;
    us4 o0, o1;
    o0.x = L[n][k+0]; o0.y = L[n][k+1]; o0.z = L[n][k+2]; o0.w = L[n][k+3];
    o1.x = L[n][k+4]; o1.y = L[n][k+5]; o1.z = L[n][k+6]; o1.w = L[n][k+7];
    *(us4*)(dst + (size_t)n*stride + k)     = o0;
    *(us4*)(dst + (size_t)n*stride + k + 4) = o1;
  }
}

// ---------------------------------------------------------------------------
// node_emb fp32 -> bf16 (read 3x by the layers; halve the stream once)
// ---------------------------------------------------------------------------
__global__ __launch_bounds__(256) void conv_nemb(
    const float* __restrict__ nemb, u16* __restrict__ nembB)
{
  int i = blockIdx.x*256 + threadIdx.x;      // 8 elems per thread, exact cover
  size_t off = (size_t)i * 8;
  f32x4 v0 = *(const f32x4*)(nemb + off);
  f32x4 v1 = *(const f32x4*)(nemb + off + 4);
  us4 o0, o1;
  o0.x = f2bf(san(v0.x)); o0.y = f2bf(san(v0.y)); o0.z = f2bf(san(v0.z)); o0.w = f2bf(san(v0.w));
  o1.x = f2bf(san(v1.x)); o1.y = f2bf(san(v1.y)); o1.z = f2bf(san(v1.z)); o1.w = f2bf(san(v1.w));
  *(us4*)(nembB + off)     = o0;
  *(us4*)(nembB + off + 4) = o1;
}

// ---------------------------------------------------------------------------
__global__ __launch_bounds__(256) void norm_users(const float* __restrict__ ufe, u16* __restrict__ X)
{
  int gid = blockIdx.x*256 + threadIdx.x;
  int row = gid >> 6, lane = gid & 63;
  float2 v = *(const float2*)(ufe + (size_t)row*128 + lane*2);
  float a = san(v.x), b = san(v.y);
  float ss = a*a + b*b;
  #pragma unroll
  for (int off = 32; off; off >>= 1) ss += __shfl_xor(ss, off, 64);
  float inv = 1.0f / fmaxf(sqrtf(ss), 1e-12f);
  *(u32*)(X + (size_t)row*128 + lane*2) = pack2(a*inv, b*inv);
}

// ---------------------------------------------------------------------------
// Items: X[50000+r] = L2norm(feat @ trans_w + trans_b)
// 64-row tiles, weights straight from global (L2-hot).
// ---------------------------------------------------------------------------
__global__ __launch_bounds__(256, 4) void trans_items(
    const float* __restrict__ feat, const u16* __restrict__ Ttw,
    const float* __restrict__ tb, u16* __restrict__ X)
{
  __shared__ u16 Af[64][136];
  __shared__ float rowss[64][8];
  __shared__ float rnorm[64];

  int t = threadIdx.x;
  int r0 = blockIdx.x * 64;
  int w = t >> 6, lane = t & 63;
  int l15 = lane & 15, q = lane >> 4;
  int m0 = (w & 1) * 64, n0 = (w >> 1) * 32;

  f32x4 acc[4][2];
  #pragma unroll
  for (int mi = 0; mi < 4; mi++)
    #pragma unroll
    for (int ni = 0; ni < 2; ni++){ acc[mi][ni].x = 0.f; acc[mi][ni].y = 0.f; acc[mi][ni].z = 0.f; acc[mi][ni].w = 0.f; }

  for (int half = 0; half < 2; half++){
    __syncthreads();
    #pragma unroll
    for (int p = 0; p < 4; p++){
      int fi = (p*256 + t)*8;
      int r = fi >> 7, c = fi & 127;
      int row = r0 + r;
      us4 o0 = {0,0,0,0}, o1 = {0,0,0,0};
      if (row < NI){
        f32x4 v0 = *(const f32x4*)(feat + (size_t)row*256 + half*128 + c);
        f32x4 v1 = *(const f32x4*)(feat + (size_t)row*256 + half*128 + c + 4);
        o0.x = f2bf(san(v0.x)); o0.y = f2bf(san(v0.y)); o0.z = f2bf(san(v0.z)); o0.w = f2bf(san(v0.w));
        o1.x = f2bf(san(v1.x)); o1.y = f2bf(san(v1.y)); o1.z = f2bf(san(v1.z)); o1.w = f2bf(san(v1.w));
      }
      *(us4*)&Af[r][c]     = o0;
      *(us4*)&Af[r][c + 4] = o1;
    }
    __syncthreads();
    #pragma unroll
    for (int kc = 0; kc < 128; kc += 32){
      s16x8 afr[4], bfr[2];
      #pragma unroll
      for (int mi = 0; mi < 4; mi++)
        afr[mi] = *(const s16x8*)(Ttw + (size_t)(m0 + 16*mi + l15)*256 + half*128 + kc + 8*q);
      #pragma unroll
      for (int ni = 0; ni < 2; ni++) bfr[ni] = *(const s16x8*)&Af[n0 + 16*ni + l15][kc + 8*q];
      #pragma unroll
      for (int mi = 0; mi < 4; mi++)
        #pragma unroll
        for (int ni = 0; ni < 2; ni++)
          acc[mi][ni] = __builtin_amdgcn_mfma_f32_16x16x32_bf16(afr[mi], bfr[ni], acc[mi][ni], 0, 0, 0);
    }
  }

  float bias[4][4];
  #pragma unroll
  for (int mi = 0; mi < 4; mi++){
    int c0 = m0 + 16*mi + 4*q;
    f32x4 bv = *(const f32x4*)(tb + c0);
    bias[mi][0] = san(bv.x); bias[mi][1] = san(bv.y); bias[mi][2] = san(bv.z); bias[mi][3] = san(bv.w);
  }
  #pragma unroll
  for (int ni = 0; ni < 2; ni++){
    float ss = 0.f;
    #pragma unroll
    for (int mi = 0; mi < 4; mi++){
      float v0 = acc[mi][ni].x + bias[mi][0];
      float v1 = acc[mi][ni].y + bias[mi][1];
      float v2 = acc[mi][ni].z + bias[mi][2];
      float v3 = acc[mi][ni].w + bias[mi][3];
      ss += v0*v0 + v1*v1 + v2*v2 + v3*v3;
    }
    rowss[n0 + 16*ni + l15][(w & 1)*4 + q] = ss;
  }
  __syncthreads();
  if (t < 64){
    float s = 0.f;
    #pragma unroll
    for (int j = 0; j < 8; j++) s += rowss[t][j];
    rnorm[t] = 1.0f / fmaxf(sqrtf(s), 1e-12f);
  }
  __syncthreads();
  #pragma unroll
  for (int mi = 0; mi < 4; mi++){
    int c0 = m0 + 16*mi + 4*q;
    #pragma unroll
    for (int ni = 0; ni < 2; ni++){
      int r = n0 + 16*ni + l15;
      int row = r0 + r;
      if (row < NI){
        float inv = rnorm[r];
        us4 o;
        o.x = f2bf((acc[mi][ni].x + bias[mi][0]) * inv);
        o.y = f2bf((acc[mi][ni].y + bias[mi][1]) * inv);
        o.z = f2bf((acc[mi][ni].z + bias[mi][2]) * inv);
        o.w = f2bf((acc[mi][ni].w + bias[mi][3]) * inv);
        *(us4*)(X + (size_t)(NU + row)*128 + c0) = o;
      }
    }
  }
}

// ---------------------------------------------------------------------------
// CSR build — LDS-sliced histogram, no global atomics.
// ---------------------------------------------------------------------------
__global__ __launch_bounds__(1024) void hist_lds(
    const int* __restrict__ dst, u32* __restrict__ countsC)
{
  __shared__ u32 cnt[HSW];
  int b = blockIdx.x;
  int s = b / HCHUNK, c = b % HCHUNK;
  int t = threadIdx.x;
  for (int i = t; i < HSW; i += 1024) cnt[i] = 0;
  __syncthreads();
  int lo = s * HSW;
  int hi = min(lo + HSW, NN);
  int e0 = c * HEPC, e1 = e0 + HEPC;
  for (int e = e0 + t*4; e < e1; e += 4096){
    int4 d4 = *(const int4*)(dst + e);
    int d0 = min(max(d4.x, 0), NN-1);
    int d1 = min(max(d4.y, 0), NN-1);
    int d2 = min(max(d4.z, 0), NN-1);
    int d3 = min(max(d4.w, 0), NN-1);
    if (d0 >= lo && d0 < hi) atomicAdd(&cnt[d0 - lo], 1u);
    if (d1 >= lo && d1 < hi) atomicAdd(&cnt[d1 - lo], 1u);
    if (d2 >= lo && d2 < hi) atomicAdd(&cnt[d2 - lo], 1u);
    if (d3 >= lo && d3 < hi) atomicAdd(&cnt[d3 - lo], 1u);
  }
  __syncthreads();
  u32* outp = countsC + (size_t)c*NN + lo;
  int w = hi - lo;
  for (int i = t; i < w; i += 1024) outp[i] = cnt[i];
}

__global__ __launch_bounds__(256) void reduce_counts(
    const u32* __restrict__ countsC, int* __restrict__ counts)
{
  int v = blockIdx.x*256 + threadIdx.x;
  if (v < NN){
    u32 sum = 0;
    #pragma unroll
    for (int c = 0; c < HCHUNK; c++) sum += countsC[(size_t)c*NN + v];
    counts[v] = (int)sum;
  }
}

// Single-block scan, wave-shuffle based: 3 barriers per 4096-chunk.
__global__ __launch_bounds__(1024) void scan_k(const int* __restrict__ counts, int* __restrict__ row_ptr){
  __shared__ int wsum[16];
  __shared__ int woff[16];
  __shared__ int tot;
  int t = threadIdx.x;
  int lane = t & 63, wid = t >> 6;
  int carry = 0;
  for (int base = 0; base < NN; base += 4096){
    int idx = base + t*4;
    int4 v = {0,0,0,0};
    if (idx < NN) v = *(const int4*)(counts + idx);
    int s4 = v.x + v.y + v.z + v.w;
    int s = s4;
    #pragma unroll
    for (int off = 1; off < 64; off <<= 1){
      int u = __shfl_up(s, off, 64);
      if (lane >= off) s += u;
    }
    if (lane == 63) wsum[wid] = s;
    __syncthreads();
    if (t < 16){
      int ws = wsum[t];
      int wscan = ws;
      #pragma unroll
      for (int off = 1; off < 16; off <<= 1){
        int u = __shfl_up(wscan, off, 64);
        if (t >= off) wscan += u;
      }
      woff[t] = wscan - ws;       // exclusive wave offset
      if (t == 15) tot = wscan;   // chunk total
    }
    __syncthreads();
    if (idx < NN){
      int e0 = carry + woff[wid] + (s - s4);
      int4 o;
      o.x = e0; o.y = e0 + v.x; o.z = o.y + v.y; o.w = o.z + v.z;
      *(int4*)(row_ptr + idx) = o;
    }
    carry += tot;
    __syncthreads();   // protect wsum/woff/tot before next chunk
  }
}

// Sliced fill: pass p handles dst in [d0,d1); esrc window stays L2-resident.
// row_ptr doubles as cursor (post-fill: row_ptr[v] == original row_ptr[v+1]).
__global__ __launch_bounds__(256) void fill_slice(
    const int* __restrict__ src, const int* __restrict__ dst,
    int* __restrict__ row_ptr, int* __restrict__ esrc, int d0, int d1)
{
  int e = blockIdx.x*256 + threadIdx.x;
  if (e < NE){
    int d = dst[e];
    if (d >= d0 && d < d1){
      d = min(max(d, 0), NN - 1);
      int pos = atomicAdd(&row_ptr[d], 1);
      pos = min(max(pos, 0), NE - 1);
      esrc[pos] = src[e];
    }
  }
}

// ---------------------------------------------------------------------------
// Standalone aggregation (used for the LAST layer only — its output layer
// overwrites X's region with fp32, so the gather must complete first).
// ---------------------------------------------------------------------------
#define ACC8(P) \
  a0 += bf2f((u16)(P.x & 0xFFFF)); a1 += bf2f((u16)(P.x >> 16)); \
  a2 += bf2f((u16)(P.y & 0xFFFF)); a3 += bf2f((u16)(P.y >> 16)); \
  a4 += bf2f((u16)(P.z & 0xFFFF)); a5 += bf2f((u16)(P.z >> 16)); \
  a6 += bf2f((u16)(P.w & 0xFFFF)); a7 += bf2f((u16)(P.w >> 16));

__global__ __launch_bounds__(256) void aggregate(
    const u16* __restrict__ X, const int* __restrict__ row_ptr,
    const int* __restrict__ esrc, u16* __restrict__ AGG)
{
  int gid = blockIdx.x*256 + threadIdx.x;
  int v = gid >> 6, lane = gid & 63;
  int sub = lane >> 4, li = lane & 15;
  int jb = (v == 0) ? 0 : row_ptr[v - 1];
  int je = row_ptr[v];
  jb = min(max(jb, 0), NE);
  je = min(max(je, jb), NE);

  float a0=0.f,a1=0.f,a2=0.f,a3=0.f,a4=0.f,a5=0.f,a6=0.f,a7=0.f;

  int j = jb + sub;
  for (; j + 12 < je; j += 16){
    int s0 = esrc[j];      s0 = min(max(s0, 0), NN - 1);
    int s1 = esrc[j + 4];  s1 = min(max(s1, 0), NN - 1);
    int s2 = esrc[j + 8];  s2 = min(max(s2, 0), NN - 1);
    int s3 = esrc[j + 12]; s3 = min(max(s3, 0), NN - 1);
    uint4 p0 = *(const uint4*)(X + (size_t)s0*128 + li*8);
    uint4 p1 = *(const uint4*)(X + (size_t)s1*128 + li*8);
    uint4 p2 = *(const uint4*)(X + (size_t)s2*128 + li*8);
    uint4 p3 = *(const uint4*)(X + (size_t)s3*128 + li*8);
    ACC8(p0); ACC8(p1); ACC8(p2); ACC8(p3);
  }
  for (; j + 4 < je; j += 8){
    int s0 = esrc[j];     s0 = min(max(s0, 0), NN - 1);
    int s1 = esrc[j + 4]; s1 = min(max(s1, 0), NN - 1);
    uint4 p0 = *(const uint4*)(X + (size_t)s0*128 + li*8);
    uint4 p1 = *(const uint4*)(X + (size_t)s1*128 + li*8);
    ACC8(p0); ACC8(p1);
  }
  for (; j < je; j += 4){
    int s0 = esrc[j]; s0 = min(max(s0, 0), NN - 1);
    uint4 p0 = *(const uint4*)(X + (size_t)s0*128 + li*8);
    ACC8(p0);
  }

  a0 += __shfl_xor(a0, 16, 64); a0 += __shfl_xor(a0, 32, 64);
  a1 += __shfl_xor(a1, 16, 64); a1 += __shfl_xor(a1, 32, 64);
  a2 += __shfl_xor(a2, 16, 64); a2 += __shfl_xor(a2, 32, 64);
  a3 += __shfl_xor(a3, 16, 64); a3 += __shfl_xor(a3, 32, 64);
  a4 += __shfl_xor(a4, 16, 64); a4 += __shfl_xor(a4, 32, 64);
  a5 += __shfl_xor(a5, 16, 64); a5 += __shfl_xor(a5, 32, 64);
  a6 += __shfl_xor(a6, 16, 64); a6 += __shfl_xor(a6, 32, 64);
  a7 += __shfl_xor(a7, 16, 64); a7 += __shfl_xor(a7, 32, 64);

  if (sub == 0){
    uint4 o;
    o.x = pack2(a0, a1); o.y = pack2(a2, a3);
    o.z = pack2(a4, a5); o.w = pack2(a6, a7);
    *(uint4*)(AGG + (size_t)v*128 + li*8) = o;
  }
}

// ---------------------------------------------------------------------------
// Shared GEMM macros (round-0 form: 4 waves, 64x64 subtiles, in-phase A loads
// — the measured best; register-prefetch (r2-r4) and 8-wave (r6) both lost).
// ---------------------------------------------------------------------------
#define ZERO_ACC() \
  { _Pragma("unroll") for (int mi = 0; mi < 4; mi++) \
      { _Pragma("unroll") for (int ni = 0; ni < 4; ni++) \
        { acc[mi][ni].x = 0.f; acc[mi][ni].y = 0.f; acc[mi][ni].z = 0.f; acc[mi][ni].w = 0.f; } } }

#define GEMMG(BARR, WBASE, WSTRIDE, WKOFF) \
  { s16x8 afr[4][4]; \
    _Pragma("unroll") for (int mi = 0; mi < 4; mi++) \
      { _Pragma("unroll") for (int kk = 0; kk < 4; kk++) \
          afr[mi][kk] = *(const s16x8*)((WBASE) + (size_t)(m0 + 16*mi + l15)*(WSTRIDE) + (WKOFF) + kk*32 + 8*q); } \
    _Pragma("unroll") for (int kk = 0; kk < 4; kk++){ \
      s16x8 bfr[4]; \
      _Pragma("unroll") for (int ni = 0; ni < 4; ni++) bfr[ni] = *(const s16x8*)&BARR[n0 + 16*ni + l15][kk*32 + 8*q]; \
      _Pragma("unroll") for (int mi = 0; mi < 4; mi++) \
        { _Pragma("unroll") for (int ni = 0; ni < 4; ni++) \
          acc[mi][ni] = __builtin_amdgcn_mfma_f32_16x16x32_bf16(afr[mi][kk], bfr[ni], acc[mi][ni], 0, 0, 0); } } }

// GEMM stages + epilogues shared by both layer kernels. Requires in scope:
// Ab, Hb, t, r0, w, lane, l15, q, m0, n0, acc, and the weight/bias pointers.
#define LAYER_BODY(NEMBB, TWI, TDI, DBF, TOI, OBF, LAST_EXPR)                  \
  /* stage 1: H^T = Tw * Agg^T */                                              \
  ZERO_ACC();                                                                  \
  GEMMG(Ab, TWI, 128, 0);                                                      \
  _Pragma("unroll")                                                            \
  for (int mi = 0; mi < 4; mi++){                                              \
    _Pragma("unroll")                                                          \
    for (int ni = 0; ni < 4; ni++){                                            \
      us4 o;                                                                   \
      o.x = f2bf(lrelu(acc[mi][ni].x));                                        \
      o.y = f2bf(lrelu(acc[mi][ni].y));                                        \
      o.z = f2bf(lrelu(acc[mi][ni].z));                                        \
      o.w = f2bf(lrelu(acc[mi][ni].w));                                        \
      *(us4*)&Hb[n0 + 16*ni + l15][m0 + 16*mi + 4*q] = o;                      \
    }                                                                          \
  }                                                                            \
  __syncthreads();                                                             \
  /* stage 2: U^T = Td * H^T */                                                \
  ZERO_ACC();                                                                  \
  GEMMG(Hb, TDI, 128, 0);                                                      \
  _Pragma("unroll")                                                            \
  for (int mi = 0; mi < 4; mi++){                                              \
    int c0 = m0 + 16*mi + 4*q;                                                 \
    f32x4 dbv = *(const f32x4*)(DBF + c0);                                     \
    float db0 = san(dbv.x), db1 = san(dbv.y), db2 = san(dbv.z), db3 = san(dbv.w); \
    _Pragma("unroll")                                                          \
    for (int ni = 0; ni < 4; ni++){                                            \
      int r = n0 + 16*ni + l15;                                                \
      int row = r0 + r;                                                        \
      float e0 = 0.f, e1 = 0.f, e2 = 0.f, e3 = 0.f;                            \
      if (row < NN){                                                           \
        us4 ne = *(const us4*)(NEMBB + (size_t)row*128 + c0);                  \
        e0 = bf2f(ne.x); e1 = bf2f(ne.y); e2 = bf2f(ne.z); e3 = bf2f(ne.w);    \
      }                                                                        \
      us4 o;                                                                   \
      o.x = f2bf(lrelu(acc[mi][ni].x + db0 + e0));                             \
      o.y = f2bf(lrelu(acc[mi][ni].y + db1 + e1));                             \
      o.z = f2bf(lrelu(acc[mi][ni].z + db2 + e2));                             \
      o.w = f2bf(lrelu(acc[mi][ni].w + db3 + e3));                             \
      *(us4*)&Ab[r][c0] = o;                                                   \
    }                                                                          \
  }                                                                            \
  __syncthreads();                                                             \
  /* stage 3: X^T = To[:,0:128]*H^T + To[:,128:256]*U^T */                     \
  ZERO_ACC();                                                                  \
  GEMMG(Hb, TOI, 256, 0);                                                      \
  GEMMG(Ab, TOI, 256, 128);

// ---------------------------------------------------------------------------
// Fused gather + dense layer (layers 0,1). 16 subgroups of 16 lanes; each
// subgroup aggregates 8 of the tile's 128 dst rows directly into Ab (no AGG
// round-trip, no separate kernel). 8 X-row loads kept in flight per subgroup.
// ---------------------------------------------------------------------------
__global__ __launch_bounds__(256, 2) void layer_fused_agg(
    const u16* __restrict__ Xin, const int* __restrict__ row_ptr,
    const int* __restrict__ esrc, const u16* __restrict__ nembB,
    const u16* __restrict__ Twi, const u16* __restrict__ Tdi,
    const float* __restrict__ dbF, const u16* __restrict__ Toi,
    const float* __restrict__ obF, u16* __restrict__ XoutB)
{
  __shared__ __align__(16) u16 Ab[128][136];
  __shared__ __align__(16) u16 Hb[128][136];

  int t = threadIdx.x;
  int r0 = blockIdx.x * 128;
  int w = t >> 6, lane = t & 63;
  int l15 = lane & 15, q = lane >> 4;
  int m0 = (w & 1) * 64, n0 = (w >> 1) * 64;
  int sg = t >> 4, li = t & 15;

  f32x4 acc[4][4];

  // ---- gather: subgroup sg aggregates nodes r = k*16 + sg into Ab[r] ----
  for (int k = 0; k < 8; k++){
    int r = k*16 + sg;
    int v = r0 + r;
    float a0=0.f,a1=0.f,a2=0.f,a3=0.f,a4=0.f,a5=0.f,a6=0.f,a7=0.f;
    if (v < NN){
      int jb = (v == 0) ? 0 : row_ptr[v - 1];
      int je = row_ptr[v];
      jb = min(max(jb, 0), NE);
      je = min(max(je, jb), NE);
      for (int j = jb; j < je; j += 8){
        uint4 pv[8];
        #pragma unroll
        for (int i = 0; i < 8; i++){
          int jj = min(j + i, je - 1);
          int s = esrc[jj]; s = min(max(s, 0), NN - 1);
          pv[i] = *(const uint4*)(Xin + (size_t)s*128 + li*8);
          if (j + i >= je){ pv[i].x = 0u; pv[i].y = 0u; pv[i].z = 0u; pv[i].w = 0u; }
        }
        #pragma unroll
        for (int i = 0; i < 8; i++){ ACC8(pv[i]); }
      }
    }
    uint4 o;
    o.x = pack2(a0, a1); o.y = pack2(a2, a3);
    o.z = pack2(a4, a5); o.w = pack2(a6, a7);
    *(uint4*)&Ab[r][li*8] = o;
  }
  __syncthreads();

  LAYER_BODY(nembB, Twi, Tdi, dbF, Toi, obF, 0)

  // bf16 epilogue
  #pragma unroll
  for (int mi = 0; mi < 4; mi++){
    int c0 = m0 + 16*mi + 4*q;
    f32x4 obv = *(const f32x4*)(obF + c0);
    float b0 = san(obv.x), b1 = san(obv.y), b2 = san(obv.z), b3 = san(obv.w);
    #pragma unroll
    for (int ni = 0; ni < 4; ni++){
      int r = n0 + 16*ni + l15;
      int row = r0 + r;
      if (row < NN){
        us4 o;
        o.x = f2bf(lrelu(acc[mi][ni].x + b0));
        o.y = f2bf(lrelu(acc[mi][ni].y + b1));
        o.z = f2bf(lrelu(acc[mi][ni].z + b2));
        o.w = f2bf(lrelu(acc[mi][ni].w + b3));
        *(us4*)(XoutB + (size_t)row*128 + c0) = o;
      }
    }
  }
}

// ---------------------------------------------------------------------------
// Unfused dense layer (last layer): reads pre-computed AGG, writes fp32 out.
// ---------------------------------------------------------------------------
__global__ __launch_bounds__(256, 2) void layer_fused(
    const u16* __restrict__ AGG, const u16* __restrict__ nembB,
    const u16* __restrict__ Twi, const u16* __restrict__ Tdi,
    const float* __restrict__ dbF, const u16* __restrict__ Toi,
    const float* __restrict__ obF, float* __restrict__ XoutF)
{
  __shared__ __align__(16) u16 Ab[128][136];
  __shared__ __align__(16) u16 Hb[128][136];

  int t = threadIdx.x;
  int r0 = blockIdx.x * 128;
  int w = t >> 6, lane = t & 63;
  int l15 = lane & 15, q = lane >> 4;
  int m0 = (w & 1) * 64, n0 = (w >> 1) * 64;

  f32x4 acc[4][4];

  // stage agg tile into Ab
  #pragma unroll
  for (int p = 0; p < 8; p++){
    int fi = (p*256 + t)*8;
    int r = fi >> 7, c = fi & 127;
    int row = r0 + r;
    us4 o0 = {0,0,0,0}, o1 = {0,0,0,0};
    if (row < NN){
      o0 = *(const us4*)(AGG + (size_t)row*128 + c);
      o1 = *(const us4*)(AGG + (size_t)row*128 + c + 4);
    }
    *(us4*)&Ab[r][c]     = o0;
    *(us4*)&Ab[r][c + 4] = o1;
  }
  __syncthreads();

  LAYER_BODY(nembB, Twi, Tdi, dbF, Toi, obF, 1)

  // fp32 epilogue
  #pragma unroll
  for (int mi = 0; mi < 4; mi++){
    int c0 = m0 + 16*mi + 4*q;
    f32x4 obv = *(const f32x4*)(obF + c0);
    float b0 = san(obv.x), b1 = san(obv.y), b2 = san(obv.z), b3 = san(obv.w);
    #pragma unroll
    for (int ni = 0; ni < 4; ni++){
      int r = n0 + 16*ni + l15;
      int row = r0 + r;
      if (row < NN){
        f32x4 o;
        o.x = lrelu(acc[mi][ni].x + b0);
        o.y = lrelu(acc[mi][ni].y + b1);
        o.z = lrelu(acc[mi][ni].z + b2);
        o.w = lrelu(acc[mi][ni].w + b3);
        *(f32x4*)(XoutF + (size_t)row*128 + c0) = o;
      }
    }
  }
}

// ---------------------------------------------------------------------------
__global__ void copy_ufe(const float4* __restrict__ s, float4* __restrict__ d, int n){
  int i = blockIdx.x*256 + threadIdx.x;
  if (i < n){
    float4 v = s[i];
    v.x = san(v.x); v.y = san(v.y); v.z = san(v.z); v.w = san(v.w);
    d[i] = v;
  }
}

// ---------------------------------------------------------------------------
extern "C" void kernel_launch(void* const* d_in, const int* in_sizes, int n_in,
                              void* d_out, int out_size, void* d_ws, size_t ws_size,
                              hipStream_t stream)
{
  const float* feat = (const float*)d_in[0];
  const float* nemb = (const float*)d_in[1];
  const int*   src  = (const int*)d_in[2];
  const int*   dst  = (const int*)d_in[3];
  const float* ufe  = (const float*)d_in[4];
  const float* tw   = (const float*)d_in[5];
  const float* tb   = (const float*)d_in[6];
  const float* wsw  = (const float*)d_in[7];
  const float* desw = (const float*)d_in[8];
  const float* desb = (const float*)d_in[9];
  const float* outw = (const float*)d_in[10];
  const float* outb = (const float*)d_in[11];

  float* out  = (float*)d_out;
  float* outU = out + (size_t)NN*128;

  // bf16 X table aliases the first 25.6 MB of d_out.
  u16* X = (u16*)out;
  // bf16 node_emb lives in the outU tail; copy_ufe overwrites it at the end.
  u16* nembB = (u16*)outU;

  char* p = (char*)d_ws;
  u16*   AGG = (u16*)p;    p += (size_t)NN*128*2;   // slot also serves as countsC and X1
  u16*   Ttw = (u16*)p;    p += (size_t)2*16384*2;
  u16*   Tw  = (u16*)p;    p += (size_t)3*16384*2;
  u16*   Td  = (u16*)p;    p += (size_t)3*16384*2;
  u16*   To  = (u16*)p;    p += (size_t)3*32768*2;
  int* row_ptr = (int*)p;  p += (size_t)100004*4;
  int* counts  = (int*)p;  p += (size_t)100000*4;
  int* esrc    = (int*)p;  p += (size_t)NE*4;
  // countsC (25.6 MB) aliases the AGG slot: dead after reduce_counts, before
  // the slot's next use as X1 (layer-0 output).
  u32* countsC = (u32*)AGG;
  u16* X1 = AGG;

  transpose_weights<<<14, 256, 0, stream>>>(tw, wsw, desw, outw, Ttw, Tw, Td, To);
  conv_nemb<<<6250, 256, 0, stream>>>(nemb, nembB);
  norm_users<<<NU/4, 256, 0, stream>>>(ufe, X);
  trans_items<<<(NI + 63)/64, 256, 0, stream>>>(feat, Ttw, tb, X);

  hist_lds<<<HSLICE*HCHUNK, 1024, 0, stream>>>(dst, countsC);
  reduce_counts<<<(NN + 255)/256, 256, 0, stream>>>(countsC, counts);
  scan_k<<<1, 1024, 0, stream>>>(counts, row_ptr);
  for (int s = 0; s < NSLICE; s++){
    fill_slice<<<(NE + 255)/256, 256, 0, stream>>>(src, dst, row_ptr, esrc,
        s*SLICEW, (s == NSLICE-1) ? NN : (s+1)*SLICEW);
  }

  int nblk = (NN + 127)/128;
  // layer 0: gather from X (d_out) -> write X1 (ws)
  layer_fused_agg<<<nblk, 256, 0, stream>>>(X, row_ptr, esrc, nembB,
      Tw, Td, desb, To, outb, X1);
  // layer 1: gather from X1 -> write X (d_out)
  layer_fused_agg<<<nblk, 256, 0, stream>>>(X1, row_ptr, esrc, nembB,
      Tw + 16384, Td + 16384, desb + 128, To + 32768, outb + 128, X);
  // layer 2: X's region becomes the fp32 output -> gather must finish first.
  aggregate<<<NN/4, 256, 0, stream>>>(X, row_ptr, esrc, AGG);
  layer_fused<<<nblk, 256, 0, stream>>>(AGG, nembB,
      Tw + 2*16384, Td + 2*16384, desb + 2*128, To + 2*32768, outb + 2*128, out);

  copy_ufe<<<(NU*128/4 + 255)/256, 256, 0, stream>>>((const float4*)ufe, (float4*)outU, NU*128/4);
}

// Round 8
// 710.424 us; speedup vs baseline: 1.2504x; 1.2504x over previous
//
#include <hip/hip_runtime.h>

#define NN 100000
#define NU 50000
#define NI 50000
#define NE 1600000
#define NSLICE 3
#define SLICEW 33334

// LDS histogram geometry
#define HSLICE 4
#define HCHUNK 64
#define HSW 25600          // counters per slice; 4*25600 >= NN
#define HEPC (NE/HCHUNK)   // edges per chunk = 25000

typedef unsigned short u16;
typedef unsigned int u32;

typedef __attribute__((ext_vector_type(8))) short s16x8;
typedef __attribute__((ext_vector_type(4))) float f32x4;
typedef __attribute__((ext_vector_type(4))) unsigned short us4;

__device__ __forceinline__ float bf2f(u16 u){
  union { u32 i; float f; } v; v.i = ((u32)u) << 16; return v.f;
}
__device__ __forceinline__ u16 f2bf(float f){
  union { float f; u32 i; } v; v.f = f;
  u32 u = v.i;
  return (u16)((u + 0x7FFFu + ((u >> 16) & 1u)) >> 16);
}
__device__ __forceinline__ u32 pack2(float lo, float hi){
  return (u32)f2bf(lo) | ((u32)f2bf(hi) << 16);
}
__device__ __forceinline__ float lrelu(float x){ return x > 0.f ? x : 0.01f * x; }
__device__ __forceinline__ float san(float v){
  union { float f; u32 i; } u; u.f = v;
  return ((u.i & 0x7F800000u) == 0x7F800000u) ? 0.f : v;
}

// ---------------------------------------------------------------------------
// Weight pre-transpose (fp32 in -> bf16 transposed out)
// ---------------------------------------------------------------------------
__global__ __launch_bounds__(256) void transpose_weights(
    const float* __restrict__ trans_w, const float* __restrict__ wsw,
    const float* __restrict__ desw, const float* __restrict__ outw,
    u16* __restrict__ Ttw, u16* __restrict__ Tw, u16* __restrict__ Td, u16* __restrict__ To)
{
  __shared__ u16 L[128][136];
  int b = blockIdx.x, t = threadIdx.x;
  const float* src; u16* dst; int stride;
  if (b < 2)      { src = trans_w + b*16384;        dst = Ttw + b*128;          stride = 256; }
  else if (b < 5) { int i = b-2; src = wsw  + i*16384; dst = Tw + i*16384;      stride = 128; }
  else if (b < 8) { int i = b-5; src = desw + i*16384; dst = Td + i*16384;      stride = 128; }
  else            { int i = (b-8)>>1, h = (b-8)&1;
                    src = outw + i*32768 + h*16384;    dst = To + i*32768 + h*128; stride = 256; }
  #pragma unroll
  for (int p = 0; p < 8; p++){
    int fi = (p*256 + t)*8;
    int r = fi >> 7, c = fi & 127;
    f32x4 v0 = *(const f32x4*)(src + r*128 + c);
    f32x4 v1 = *(const f32x4*)(src + r*128 + c + 4);
    L[c+0][r] = f2bf(san(v0.x)); L[c+1][r] = f2bf(san(v0.y));
    L[c+2][r] = f2bf(san(v0.z)); L[c+3][r] = f2bf(san(v0.w));
    L[c+4][r] = f2bf(san(v1.x)); L[c+5][r] = f2bf(san(v1.y));
    L[c+6][r] = f2bf(san(v1.z)); L[c+7][r] = f2bf(san(v1.w));
  }
  __syncthreads();
  #pragma unroll
  for (int p = 0; p < 8; p++){
    int fi = (p*256 + t)*8;
    int n = fi >> 7, k = fi & 127;
    us4 o0, o1;
    o0.x = L[n][k+0]; o0.y = L[n][k+1]; o0.z = L[n][k+2]; o0.w = L[n][k+3];
    o1.x = L[n][k+4]; o1.y = L[n][k+5]; o1.z = L[n][k+6]; o1.w = L[n][k+7];
    *(us4*)(dst + (size_t)n*stride + k)     = o0;
    *(us4*)(dst + (size_t)n*stride + k + 4) = o1;
  }
}

// ---------------------------------------------------------------------------
// node_emb fp32 -> bf16 (read 3x by the layers; halve the stream once)
// ---------------------------------------------------------------------------
__global__ __launch_bounds__(256) void conv_nemb(
    const float* __restrict__ nemb, u16* __restrict__ nembB)
{
  int i = blockIdx.x*256 + threadIdx.x;      // 8 elems per thread, exact cover
  size_t off = (size_t)i * 8;
  f32x4 v0 = *(const f32x4*)(nemb + off);
  f32x4 v1 = *(const f32x4*)(nemb + off + 4);
  us4 o0, o1;
  o0.x = f2bf(san(v0.x)); o0.y = f2bf(san(v0.y)); o0.z = f2bf(san(v0.z)); o0.w = f2bf(san(v0.w));
  o1.x = f2bf(san(v1.x)); o1.y = f2bf(san(v1.y)); o1.z = f2bf(san(v1.z)); o1.w = f2bf(san(v1.w));
  *(us4*)(nembB + off)     = o0;
  *(us4*)(nembB + off + 4) = o1;
}

// ---------------------------------------------------------------------------
__global__ __launch_bounds__(256) void norm_users(const float* __restrict__ ufe, u16* __restrict__ X)
{
  int gid = blockIdx.x*256 + threadIdx.x;
  int row = gid >> 6, lane = gid & 63;
  float2 v = *(const float2*)(ufe + (size_t)row*128 + lane*2);
  float a = san(v.x), b = san(v.y);
  float ss = a*a + b*b;
  #pragma unroll
  for (int off = 32; off; off >>= 1) ss += __shfl_xor(ss, off, 64);
  float inv = 1.0f / fmaxf(sqrtf(ss), 1e-12f);
  *(u32*)(X + (size_t)row*128 + lane*2) = pack2(a*inv, b*inv);
}

// ---------------------------------------------------------------------------
// Items: X[50000+r] = L2norm(feat @ trans_w + trans_b)
// 64-row tiles, weights straight from global (L2-hot).
// ---------------------------------------------------------------------------
__global__ __launch_bounds__(256, 4) void trans_items(
    const float* __restrict__ feat, const u16* __restrict__ Ttw,
    const float* __restrict__ tb, u16* __restrict__ X)
{
  __shared__ u16 Af[64][136];
  __shared__ float rowss[64][8];
  __shared__ float rnorm[64];

  int t = threadIdx.x;
  int r0 = blockIdx.x * 64;
  int w = t >> 6, lane = t & 63;
  int l15 = lane & 15, q = lane >> 4;
  int m0 = (w & 1) * 64, n0 = (w >> 1) * 32;

  f32x4 acc[4][2];
  #pragma unroll
  for (int mi = 0; mi < 4; mi++)
    #pragma unroll
    for (int ni = 0; ni < 2; ni++){ acc[mi][ni].x = 0.f; acc[mi][ni].y = 0.f; acc[mi][ni].z = 0.f; acc[mi][ni].w = 0.f; }

  for (int half = 0; half < 2; half++){
    __syncthreads();
    #pragma unroll
    for (int p = 0; p < 4; p++){
      int fi = (p*256 + t)*8;
      int r = fi >> 7, c = fi & 127;
      int row = r0 + r;
      us4 o0 = {0,0,0,0}, o1 = {0,0,0,0};
      if (row < NI){
        f32x4 v0 = *(const f32x4*)(feat + (size_t)row*256 + half*128 + c);
        f32x4 v1 = *(const f32x4*)(feat + (size_t)row*256 + half*128 + c + 4);
        o0.x = f2bf(san(v0.x)); o0.y = f2bf(san(v0.y)); o0.z = f2bf(san(v0.z)); o0.w = f2bf(san(v0.w));
        o1.x = f2bf(san(v1.x)); o1.y = f2bf(san(v1.y)); o1.z = f2bf(san(v1.z)); o1.w = f2bf(san(v1.w));
      }
      *(us4*)&Af[r][c]     = o0;
      *(us4*)&Af[r][c + 4] = o1;
    }
    __syncthreads();
    #pragma unroll
    for (int kc = 0; kc < 128; kc += 32){
      s16x8 afr[4], bfr[2];
      #pragma unroll
      for (int mi = 0; mi < 4; mi++)
        afr[mi] = *(const s16x8*)(Ttw + (size_t)(m0 + 16*mi + l15)*256 + half*128 + kc + 8*q);
      #pragma unroll
      for (int ni = 0; ni < 2; ni++) bfr[ni] = *(const s16x8*)&Af[n0 + 16*ni + l15][kc + 8*q];
      #pragma unroll
      for (int mi = 0; mi < 4; mi++)
        #pragma unroll
        for (int ni = 0; ni < 2; ni++)
          acc[mi][ni] = __builtin_amdgcn_mfma_f32_16x16x32_bf16(afr[mi], bfr[ni], acc[mi][ni], 0, 0, 0);
    }
  }

  float bias[4][4];
  #pragma unroll
  for (int mi = 0; mi < 4; mi++){
    int c0 = m0 + 16*mi + 4*q;
    f32x4 bv = *(const f32x4*)(tb + c0);
    bias[mi][0] = san(bv.x); bias[mi][1] = san(bv.y); bias[mi][2] = san(bv.z); bias[mi][3] = san(bv.w);
  }
  #pragma unroll
  for (int ni = 0; ni < 2; ni++){
    float ss = 0.f;
    #pragma unroll
    for (int mi = 0; mi < 4; mi++){
      float v0 = acc[mi][ni].x + bias[mi][0];
      float v1 = acc[mi][ni].y + bias[mi][1];
      float v2 = acc[mi][ni].z + bias[mi][2];
      float v3 = acc[mi][ni].w + bias[mi][3];
      ss += v0*v0 + v1*v1 + v2*v2 + v3*v3;
    }
    rowss[n0 + 16*ni + l15][(w & 1)*4 + q] = ss;
  }
  __syncthreads();
  if (t < 64){
    float s = 0.f;
    #pragma unroll
    for (int j = 0; j < 8; j++) s += rowss[t][j];
    rnorm[t] = 1.0f / fmaxf(sqrtf(s), 1e-12f);
  }
  __syncthreads();
  #pragma unroll
  for (int mi = 0; mi < 4; mi++){
    int c0 = m0 + 16*mi + 4*q;
    #pragma unroll
    for (int ni = 0; ni < 2; ni++){
      int r = n0 + 16*ni + l15;
      int row = r0 + r;
      if (row < NI){
        float inv = rnorm[r];
        us4 o;
        o.x = f2bf((acc[mi][ni].x + bias[mi][0]) * inv);
        o.y = f2bf((acc[mi][ni].y + bias[mi][1]) * inv);
        o.z = f2bf((acc[mi][ni].z + bias[mi][2]) * inv);
        o.w = f2bf((acc[mi][ni].w + bias[mi][3]) * inv);
        *(us4*)(X + (size_t)(NU + row)*128 + c0) = o;
      }
    }
  }
}

// ---------------------------------------------------------------------------
// CSR build — LDS-sliced histogram, no global atomics.
// ---------------------------------------------------------------------------
__global__ __launch_bounds__(1024) void hist_lds(
    const int* __restrict__ dst, u32* __restrict__ countsC)
{
  __shared__ u32 cnt[HSW];
  int b = blockIdx.x;
  int s = b / HCHUNK, c = b % HCHUNK;
  int t = threadIdx.x;
  for (int i = t; i < HSW; i += 1024) cnt[i] = 0;
  __syncthreads();
  int lo = s * HSW;
  int hi = min(lo + HSW, NN);
  int e0 = c * HEPC, e1 = e0 + HEPC;
  for (int e = e0 + t*4; e < e1; e += 4096){
    int4 d4 = *(const int4*)(dst + e);
    int d0 = min(max(d4.x, 0), NN-1);
    int d1 = min(max(d4.y, 0), NN-1);
    int d2 = min(max(d4.z, 0), NN-1);
    int d3 = min(max(d4.w, 0), NN-1);
    if (d0 >= lo && d0 < hi) atomicAdd(&cnt[d0 - lo], 1u);
    if (d1 >= lo && d1 < hi) atomicAdd(&cnt[d1 - lo], 1u);
    if (d2 >= lo && d2 < hi) atomicAdd(&cnt[d2 - lo], 1u);
    if (d3 >= lo && d3 < hi) atomicAdd(&cnt[d3 - lo], 1u);
  }
  __syncthreads();
  u32* outp = countsC + (size_t)c*NN + lo;
  int w = hi - lo;
  for (int i = t; i < w; i += 1024) outp[i] = cnt[i];
}

__global__ __launch_bounds__(256) void reduce_counts(
    const u32* __restrict__ countsC, int* __restrict__ counts)
{
  int v = blockIdx.x*256 + threadIdx.x;
  if (v < NN){
    u32 sum = 0;
    #pragma unroll
    for (int c = 0; c < HCHUNK; c++) sum += countsC[(size_t)c*NN + v];
    counts[v] = (int)sum;
  }
}

// Single-block scan, wave-shuffle based: 3 barriers per 4096-chunk.
__global__ __launch_bounds__(1024) void scan_k(const int* __restrict__ counts, int* __restrict__ row_ptr){
  __shared__ int wsum[16];
  __shared__ int woff[16];
  __shared__ int tot;
  int t = threadIdx.x;
  int lane = t & 63, wid = t >> 6;
  int carry = 0;
  for (int base = 0; base < NN; base += 4096){
    int idx = base + t*4;
    int4 v = {0,0,0,0};
    if (idx < NN) v = *(const int4*)(counts + idx);
    int s4 = v.x + v.y + v.z + v.w;
    int s = s4;
    #pragma unroll
    for (int off = 1; off < 64; off <<= 1){
      int u = __shfl_up(s, off, 64);
      if (lane >= off) s += u;
    }
    if (lane == 63) wsum[wid] = s;
    __syncthreads();
    if (t < 16){
      int ws = wsum[t];
      int wscan = ws;
      #pragma unroll
      for (int off = 1; off < 16; off <<= 1){
        int u = __shfl_up(wscan, off, 64);
        if (t >= off) wscan += u;
      }
      woff[t] = wscan - ws;       // exclusive wave offset
      if (t == 15) tot = wscan;   // chunk total
    }
    __syncthreads();
    if (idx < NN){
      int e0 = carry + woff[wid] + (s - s4);
      int4 o;
      o.x = e0; o.y = e0 + v.x; o.z = o.y + v.y; o.w = o.z + v.z;
      *(int4*)(row_ptr + idx) = o;
    }
    carry += tot;
    __syncthreads();   // protect wsum/woff/tot before next chunk
  }
}

// Sliced fill: pass p handles dst in [d0,d1); esrc window stays L2-resident.
// row_ptr doubles as cursor (post-fill: row_ptr[v] == original row_ptr[v+1]).
__global__ __launch_bounds__(256) void fill_slice(
    const int* __restrict__ src, const int* __restrict__ dst,
    int* __restrict__ row_ptr, int* __restrict__ esrc, int d0, int d1)
{
  int e = blockIdx.x*256 + threadIdx.x;
  if (e < NE){
    int d = dst[e];
    if (d >= d0 && d < d1){
      d = min(max(d, 0), NN - 1);
      int pos = atomicAdd(&row_ptr[d], 1);
      pos = min(max(pos, 0), NE - 1);
      esrc[pos] = src[e];
    }
  }
}

// ---------------------------------------------------------------------------
// Aggregation: one wave per node; quarter-wave (16 lanes x 16B) per edge,
// up to 16 edges in flight per wave; shuffle-reduce across sub-groups.
// (Standalone — the r7 in-layer fusion measured 210 us/dispatch with 188 MB
// FETCH: fused gather at 2 blocks/CU wrecks L2 locality. Keep separate.)
// ---------------------------------------------------------------------------
#define ACC8(P) \
  a0 += bf2f((u16)(P.x & 0xFFFF)); a1 += bf2f((u16)(P.x >> 16)); \
  a2 += bf2f((u16)(P.y & 0xFFFF)); a3 += bf2f((u16)(P.y >> 16)); \
  a4 += bf2f((u16)(P.z & 0xFFFF)); a5 += bf2f((u16)(P.z >> 16)); \
  a6 += bf2f((u16)(P.w & 0xFFFF)); a7 += bf2f((u16)(P.w >> 16));

__global__ __launch_bounds__(256) void aggregate(
    const u16* __restrict__ X, const int* __restrict__ row_ptr,
    const int* __restrict__ esrc, u16* __restrict__ AGG)
{
  int gid = blockIdx.x*256 + threadIdx.x;
  int v = gid >> 6, lane = gid & 63;
  int sub = lane >> 4, li = lane & 15;
  int jb = (v == 0) ? 0 : row_ptr[v - 1];
  int je = row_ptr[v];
  jb = min(max(jb, 0), NE);
  je = min(max(je, jb), NE);

  float a0=0.f,a1=0.f,a2=0.f,a3=0.f,a4=0.f,a5=0.f,a6=0.f,a7=0.f;

  int j = jb + sub;
  for (; j + 12 < je; j += 16){
    int s0 = esrc[j];      s0 = min(max(s0, 0), NN - 1);
    int s1 = esrc[j + 4];  s1 = min(max(s1, 0), NN - 1);
    int s2 = esrc[j + 8];  s2 = min(max(s2, 0), NN - 1);
    int s3 = esrc[j + 12]; s3 = min(max(s3, 0), NN - 1);
    uint4 p0 = *(const uint4*)(X + (size_t)s0*128 + li*8);
    uint4 p1 = *(const uint4*)(X + (size_t)s1*128 + li*8);
    uint4 p2 = *(const uint4*)(X + (size_t)s2*128 + li*8);
    uint4 p3 = *(const uint4*)(X + (size_t)s3*128 + li*8);
    ACC8(p0); ACC8(p1); ACC8(p2); ACC8(p3);
  }
  for (; j + 4 < je; j += 8){
    int s0 = esrc[j];     s0 = min(max(s0, 0), NN - 1);
    int s1 = esrc[j + 4]; s1 = min(max(s1, 0), NN - 1);
    uint4 p0 = *(const uint4*)(X + (size_t)s0*128 + li*8);
    uint4 p1 = *(const uint4*)(X + (size_t)s1*128 + li*8);
    ACC8(p0); ACC8(p1);
  }
  for (; j < je; j += 4){
    int s0 = esrc[j]; s0 = min(max(s0, 0), NN - 1);
    uint4 p0 = *(const uint4*)(X + (size_t)s0*128 + li*8);
    ACC8(p0);
  }

  a0 += __shfl_xor(a0, 16, 64); a0 += __shfl_xor(a0, 32, 64);
  a1 += __shfl_xor(a1, 16, 64); a1 += __shfl_xor(a1, 32, 64);
  a2 += __shfl_xor(a2, 16, 64); a2 += __shfl_xor(a2, 32, 64);
  a3 += __shfl_xor(a3, 16, 64); a3 += __shfl_xor(a3, 32, 64);
  a4 += __shfl_xor(a4, 16, 64); a4 += __shfl_xor(a4, 32, 64);
  a5 += __shfl_xor(a5, 16, 64); a5 += __shfl_xor(a5, 32, 64);
  a6 += __shfl_xor(a6, 16, 64); a6 += __shfl_xor(a6, 32, 64);
  a7 += __shfl_xor(a7, 16, 64); a7 += __shfl_xor(a7, 32, 64);

  if (sub == 0){
    uint4 o;
    o.x = pack2(a0, a1); o.y = pack2(a2, a3);
    o.z = pack2(a4, a5); o.w = pack2(a6, a7);
    *(uint4*)(AGG + (size_t)v*128 + li*8) = o;
  }
}

// ---------------------------------------------------------------------------
// Fused dense layer — exact round-0 structure (the measured best: 72 us).
// 4 waves, 64x64 output sub-tiles, weight A-fragments loaded in-phase from
// global (L2-hot). Geometry variants all regressed: 64-row tile (r1, +8),
// register cross-phase prefetch (r2-r4, +8), 8-wave split (r6, +10),
// fused gather (r7, +130).
// ---------------------------------------------------------------------------
__global__ __launch_bounds__(256, 2) void layer_fused(
    const u16* __restrict__ AGG, const u16* __restrict__ nembB,
    const u16* __restrict__ Twi, const u16* __restrict__ Tdi,
    const float* __restrict__ dbF, const u16* __restrict__ Toi,
    const float* __restrict__ obF, u16* __restrict__ XoutB,
    float* __restrict__ XoutF, int last)
{
  __shared__ __align__(16) u16 Ab[128][136];   // agg (stage1 B), then u (stage3b B)
  __shared__ __align__(16) u16 Hb[128][136];   // h   (stage2/3a B)

  int t = threadIdx.x;
  int r0 = blockIdx.x * 128;
  int w = t >> 6, lane = t & 63;
  int l15 = lane & 15, q = lane >> 4;
  int m0 = (w & 1) * 64, n0 = (w >> 1) * 64;

  f32x4 acc[4][4];

#define ZERO_ACC() \
  { _Pragma("unroll") for (int mi = 0; mi < 4; mi++) \
      { _Pragma("unroll") for (int ni = 0; ni < 4; ni++) \
        { acc[mi][ni].x = 0.f; acc[mi][ni].y = 0.f; acc[mi][ni].z = 0.f; acc[mi][ni].w = 0.f; } } }

#define GEMMG(BARR, WBASE, WSTRIDE, WKOFF) \
  { s16x8 afr[4][4]; \
    _Pragma("unroll") for (int mi = 0; mi < 4; mi++) \
      { _Pragma("unroll") for (int kk = 0; kk < 4; kk++) \
          afr[mi][kk] = *(const s16x8*)((WBASE) + (size_t)(m0 + 16*mi + l15)*(WSTRIDE) + (WKOFF) + kk*32 + 8*q); } \
    _Pragma("unroll") for (int kk = 0; kk < 4; kk++){ \
      s16x8 bfr[4]; \
      _Pragma("unroll") for (int ni = 0; ni < 4; ni++) bfr[ni] = *(const s16x8*)&BARR[n0 + 16*ni + l15][kk*32 + 8*q]; \
      _Pragma("unroll") for (int mi = 0; mi < 4; mi++) \
        { _Pragma("unroll") for (int ni = 0; ni < 4; ni++) \
          acc[mi][ni] = __builtin_amdgcn_mfma_f32_16x16x32_bf16(afr[mi][kk], bfr[ni], acc[mi][ni], 0, 0, 0); } } }

  // stage agg tile into Ab
  #pragma unroll
  for (int p = 0; p < 8; p++){
    int fi = (p*256 + t)*8;
    int r = fi >> 7, c = fi & 127;
    int row = r0 + r;
    us4 o0 = {0,0,0,0}, o1 = {0,0,0,0};
    if (row < NN){
      o0 = *(const us4*)(AGG + (size_t)row*128 + c);
      o1 = *(const us4*)(AGG + (size_t)row*128 + c + 4);
    }
    *(us4*)&Ab[r][c]     = o0;
    *(us4*)&Ab[r][c + 4] = o1;
  }
  __syncthreads();

  // stage 1: H^T = Tw * Agg^T
  ZERO_ACC();
  GEMMG(Ab, Twi, 128, 0);

  // write h (lrelu) into Hb
  #pragma unroll
  for (int mi = 0; mi < 4; mi++){
    #pragma unroll
    for (int ni = 0; ni < 4; ni++){
      us4 o;
      o.x = f2bf(lrelu(acc[mi][ni].x));
      o.y = f2bf(lrelu(acc[mi][ni].y));
      o.z = f2bf(lrelu(acc[mi][ni].z));
      o.w = f2bf(lrelu(acc[mi][ni].w));
      *(us4*)&Hb[n0 + 16*ni + l15][m0 + 16*mi + 4*q] = o;
    }
  }
  __syncthreads();   // Hb complete; also guarantees all stage-1 reads of Ab done

  // stage 2: U^T = Td * H^T
  ZERO_ACC();
  GEMMG(Hb, Tdi, 128, 0);

  // write u = lrelu(. + des_b + node_emb) into Ab
  #pragma unroll
  for (int mi = 0; mi < 4; mi++){
    int c0 = m0 + 16*mi + 4*q;
    f32x4 dbv = *(const f32x4*)(dbF + c0);
    float db0 = san(dbv.x), db1 = san(dbv.y), db2 = san(dbv.z), db3 = san(dbv.w);
    #pragma unroll
    for (int ni = 0; ni < 4; ni++){
      int r = n0 + 16*ni + l15;
      int row = r0 + r;
      float e0 = 0.f, e1 = 0.f, e2 = 0.f, e3 = 0.f;
      if (row < NN){
        us4 ne = *(const us4*)(nembB + (size_t)row*128 + c0);
        e0 = bf2f(ne.x); e1 = bf2f(ne.y); e2 = bf2f(ne.z); e3 = bf2f(ne.w);
      }
      us4 o;
      o.x = f2bf(lrelu(acc[mi][ni].x + db0 + e0));
      o.y = f2bf(lrelu(acc[mi][ni].y + db1 + e1));
      o.z = f2bf(lrelu(acc[mi][ni].z + db2 + e2));
      o.w = f2bf(lrelu(acc[mi][ni].w + db3 + e3));
      *(us4*)&Ab[r][c0] = o;
    }
  }
  __syncthreads();   // u complete

  // stage 3: X^T = To[:,0:128]*H^T + To[:,128:256]*U^T
  ZERO_ACC();
  GEMMG(Hb, Toi, 256, 0);
  GEMMG(Ab, Toi, 256, 128);

  #pragma unroll
  for (int mi = 0; mi < 4; mi++){
    int c0 = m0 + 16*mi + 4*q;
    f32x4 obv = *(const f32x4*)(obF + c0);
    float b0 = san(obv.x), b1 = san(obv.y), b2 = san(obv.z), b3 = san(obv.w);
    #pragma unroll
    for (int ni = 0; ni < 4; ni++){
      int r = n0 + 16*ni + l15;
      int row = r0 + r;
      if (row < NN){
        if (last){
          f32x4 o;
          o.x = lrelu(acc[mi][ni].x + b0);
          o.y = lrelu(acc[mi][ni].y + b1);
          o.z = lrelu(acc[mi][ni].z + b2);
          o.w = lrelu(acc[mi][ni].w + b3);
          *(f32x4*)(XoutF + (size_t)row*128 + c0) = o;
        } else {
          us4 o;
          o.x = f2bf(lrelu(acc[mi][ni].x + b0));
          o.y = f2bf(lrelu(acc[mi][ni].y + b1));
          o.z = f2bf(lrelu(acc[mi][ni].z + b2));
          o.w = f2bf(lrelu(acc[mi][ni].w + b3));
          *(us4*)(XoutB + (size_t)row*128 + c0) = o;
        }
      }
    }
  }
#undef ZERO_ACC
#undef GEMMG
}

// ---------------------------------------------------------------------------
__global__ void copy_ufe(const float4* __restrict__ s, float4* __restrict__ d, int n){
  int i = blockIdx.x*256 + threadIdx.x;
  if (i < n){
    float4 v = s[i];
    v.x = san(v.x); v.y = san(v.y); v.z = san(v.z); v.w = san(v.w);
    d[i] = v;
  }
}

// ---------------------------------------------------------------------------
extern "C" void kernel_launch(void* const* d_in, const int* in_sizes, int n_in,
                              void* d_out, int out_size, void* d_ws, size_t ws_size,
                              hipStream_t stream)
{
  const float* feat = (const float*)d_in[0];
  const float* nemb = (const float*)d_in[1];
  const int*   src  = (const int*)d_in[2];
  const int*   dst  = (const int*)d_in[3];
  const float* ufe  = (const float*)d_in[4];
  const float* tw   = (const float*)d_in[5];
  const float* tb   = (const float*)d_in[6];
  const float* wsw  = (const float*)d_in[7];
  const float* desw = (const float*)d_in[8];
  const float* desb = (const float*)d_in[9];
  const float* outw = (const float*)d_in[10];
  const float* outb = (const float*)d_in[11];

  float* out  = (float*)d_out;
  float* outU = out + (size_t)NN*128;

  // bf16 X table aliases the first 25.6 MB of d_out; layer 2 overwrites the
  // full region with the fp32 result after its aggregate consumed X.
  u16* X = (u16*)out;
  // bf16 node_emb lives in the outU tail (25.6 MB); copy_ufe overwrites it
  // at the very end.
  u16* nembB = (u16*)outU;

  char* p = (char*)d_ws;
  u16*   AGG = (u16*)p;    p += (size_t)NN*128*2;
  u16*   Ttw = (u16*)p;    p += (size_t)2*16384*2;
  u16*   Tw  = (u16*)p;    p += (size_t)3*16384*2;
  u16*   Td  = (u16*)p;    p += (size_t)3*16384*2;
  u16*   To  = (u16*)p;    p += (size_t)3*32768*2;
  int* row_ptr = (int*)p;  p += (size_t)100004*4;
  int* counts  = (int*)p;  p += (size_t)100000*4;
  int* esrc    = (int*)p;  p += (size_t)NE*4;
  // countsC (HCHUNK*NN u32 = 25.6 MB) aliases AGG: dead after reduce_counts,
  // long before aggregate first writes AGG.
  u32* countsC = (u32*)AGG;

  transpose_weights<<<14, 256, 0, stream>>>(tw, wsw, desw, outw, Ttw, Tw, Td, To);
  conv_nemb<<<6250, 256, 0, stream>>>(nemb, nembB);
  norm_users<<<NU/4, 256, 0, stream>>>(ufe, X);
  trans_items<<<(NI + 63)/64, 256, 0, stream>>>(feat, Ttw, tb, X);

  hist_lds<<<HSLICE*HCHUNK, 1024, 0, stream>>>(dst, countsC);
  reduce_counts<<<(NN + 255)/256, 256, 0, stream>>>(countsC, counts);
  scan_k<<<1, 1024, 0, stream>>>(counts, row_ptr);
  for (int s = 0; s < NSLICE; s++){
    fill_slice<<<(NE + 255)/256, 256, 0, stream>>>(src, dst, row_ptr, esrc,
        s*SLICEW, (s == NSLICE-1) ? NN : (s+1)*SLICEW);
  }

  for (int i = 0; i < 3; i++){
    aggregate<<<NN/4, 256, 0, stream>>>(X, row_ptr, esrc, AGG);
    layer_fused<<<(NN + 127)/128, 256, 0, stream>>>(AGG, nembB,
        Tw + (size_t)i*16384, Td + (size_t)i*16384, desb + (size_t)i*128,
        To + (size_t)i*32768, outb + (size_t)i*128, X, out, (i == 2) ? 1 : 0);
  }
  copy_ufe<<<(NU*128/4 + 255)/256, 256, 0, stream>>>((const float4*)ufe, (float4*)outU, NU*128/4);
}

// Round 9
// 693.210 us; speedup vs baseline: 1.2814x; 1.0248x over previous
//
#include <hip/hip_runtime.h>

#define NN 100000
#define NU 50000
#define NI 50000
#define NE 1600000
#define NSLICE 2
#define SLICEW 50000

// LDS histogram geometry
#define HSLICE 4
#define HCHUNK 64
#define HSW 25600          // counters per slice; 4*25600 >= NN
#define HEPC (NE/HCHUNK)   // edges per chunk = 25000

// prep kernel block ranges
#define PREP_TW 14
#define PREP_CONV 6250
#define PREP_NORM 12500

typedef unsigned short u16;
typedef unsigned int u32;

typedef __attribute__((ext_vector_type(8))) short s16x8;
typedef __attribute__((ext_vector_type(4))) float f32x4;
typedef __attribute__((ext_vector_type(4))) unsigned short us4;

__device__ __forceinline__ float bf2f(u16 u){
  union { u32 i; float f; } v; v.i = ((u32)u) << 16; return v.f;
}
__device__ __forceinline__ u16 f2bf(float f){
  union { float f; u32 i; } v; v.f = f;
  u32 u = v.i;
  return (u16)((u + 0x7FFFu + ((u >> 16) & 1u)) >> 16);
}
__device__ __forceinline__ u32 pack2(float lo, float hi){
  return (u32)f2bf(lo) | ((u32)f2bf(hi) << 16);
}
__device__ __forceinline__ float lrelu(float x){ return x > 0.f ? x : 0.01f * x; }
__device__ __forceinline__ float san(float v){
  union { float f; u32 i; } u; u.f = v;
  return ((u.i & 0x7F800000u) == 0x7F800000u) ? 0.f : v;
}

// ---------------------------------------------------------------------------
// prep: fused {weight transpose | node_emb->bf16 | user row-norm}.
// Branch is block-uniform; barriers only inside the transpose branch.
// ---------------------------------------------------------------------------
__global__ __launch_bounds__(256) void prep(
    const float* __restrict__ trans_w, const float* __restrict__ wsw,
    const float* __restrict__ desw, const float* __restrict__ outw,
    u16* __restrict__ Ttw, u16* __restrict__ Tw, u16* __restrict__ Td, u16* __restrict__ To,
    const float* __restrict__ nemb, u16* __restrict__ nembB,
    const float* __restrict__ ufe, u16* __restrict__ X)
{
  __shared__ u16 L[128][136];
  int b = blockIdx.x, t = threadIdx.x;

  if (b < PREP_TW){
    const float* src; u16* dst; int stride;
    if (b < 2)      { src = trans_w + b*16384;        dst = Ttw + b*128;          stride = 256; }
    else if (b < 5) { int i = b-2; src = wsw  + i*16384; dst = Tw + i*16384;      stride = 128; }
    else if (b < 8) { int i = b-5; src = desw + i*16384; dst = Td + i*16384;      stride = 128; }
    else            { int i = (b-8)>>1, h = (b-8)&1;
                      src = outw + i*32768 + h*16384;    dst = To + i*32768 + h*128; stride = 256; }
    #pragma unroll
    for (int p = 0; p < 8; p++){
      int fi = (p*256 + t)*8;
      int r = fi >> 7, c = fi & 127;
      f32x4 v0 = *(const f32x4*)(src + r*128 + c);
      f32x4 v1 = *(const f32x4*)(src + r*128 + c + 4);
      L[c+0][r] = f2bf(san(v0.x)); L[c+1][r] = f2bf(san(v0.y));
      L[c+2][r] = f2bf(san(v0.z)); L[c+3][r] = f2bf(san(v0.w));
      L[c+4][r] = f2bf(san(v1.x)); L[c+5][r] = f2bf(san(v1.y));
      L[c+6][r] = f2bf(san(v1.z)); L[c+7][r] = f2bf(san(v1.w));
    }
    __syncthreads();
    #pragma unroll
    for (int p = 0; p < 8; p++){
      int fi = (p*256 + t)*8;
      int n = fi >> 7, k = fi & 127;
      us4 o0, o1;
      o0.x = L[n][k+0]; o0.y = L[n][k+1]; o0.z = L[n][k+2]; o0.w = L[n][k+3];
      o1.x = L[n][k+4]; o1.y = L[n][k+5]; o1.z = L[n][k+6]; o1.w = L[n][k+7];
      *(us4*)(dst + (size_t)n*stride + k)     = o0;
      *(us4*)(dst + (size_t)n*stride + k + 4) = o1;
    }
  } else if (b < PREP_TW + PREP_CONV){
    int i = (b - PREP_TW)*256 + t;          // 8 elems per thread, exact cover
    size_t off = (size_t)i * 8;
    f32x4 v0 = *(const f32x4*)(nemb + off);
    f32x4 v1 = *(const f32x4*)(nemb + off + 4);
    us4 o0, o1;
    o0.x = f2bf(san(v0.x)); o0.y = f2bf(san(v0.y)); o0.z = f2bf(san(v0.z)); o0.w = f2bf(san(v0.w));
    o1.x = f2bf(san(v1.x)); o1.y = f2bf(san(v1.y)); o1.z = f2bf(san(v1.z)); o1.w = f2bf(san(v1.w));
    *(us4*)(nembB + off)     = o0;
    *(us4*)(nembB + off + 4) = o1;
  } else {
    int gid = (b - PREP_TW - PREP_CONV)*256 + t;
    int row = gid >> 6, lane = gid & 63;
    float2 v = *(const float2*)(ufe + (size_t)row*128 + lane*2);
    float a = san(v.x), bb = san(v.y);
    float ss = a*a + bb*bb;
    #pragma unroll
    for (int off = 32; off; off >>= 1) ss += __shfl_xor(ss, off, 64);
    float inv = 1.0f / fmaxf(sqrtf(ss), 1e-12f);
    *(u32*)(X + (size_t)row*128 + lane*2) = pack2(a*inv, bb*inv);
  }
}

// ---------------------------------------------------------------------------
// Items: X[50000+r] = L2norm(feat @ trans_w + trans_b)
// 64-row tiles, weights straight from global (L2-hot).
// ---------------------------------------------------------------------------
__global__ __launch_bounds__(256, 4) void trans_items(
    const float* __restrict__ feat, const u16* __restrict__ Ttw,
    const float* __restrict__ tb, u16* __restrict__ X)
{
  __shared__ u16 Af[64][136];
  __shared__ float rowss[64][8];
  __shared__ float rnorm[64];

  int t = threadIdx.x;
  int r0 = blockIdx.x * 64;
  int w = t >> 6, lane = t & 63;
  int l15 = lane & 15, q = lane >> 4;
  int m0 = (w & 1) * 64, n0 = (w >> 1) * 32;

  f32x4 acc[4][2];
  #pragma unroll
  for (int mi = 0; mi < 4; mi++)
    #pragma unroll
    for (int ni = 0; ni < 2; ni++){ acc[mi][ni].x = 0.f; acc[mi][ni].y = 0.f; acc[mi][ni].z = 0.f; acc[mi][ni].w = 0.f; }

  for (int half = 0; half < 2; half++){
    __syncthreads();
    #pragma unroll
    for (int p = 0; p < 4; p++){
      int fi = (p*256 + t)*8;
      int r = fi >> 7, c = fi & 127;
      int row = r0 + r;
      us4 o0 = {0,0,0,0}, o1 = {0,0,0,0};
      if (row < NI){
        f32x4 v0 = *(const f32x4*)(feat + (size_t)row*256 + half*128 + c);
        f32x4 v1 = *(const f32x4*)(feat + (size_t)row*256 + half*128 + c + 4);
        o0.x = f2bf(san(v0.x)); o0.y = f2bf(san(v0.y)); o0.z = f2bf(san(v0.z)); o0.w = f2bf(san(v0.w));
        o1.x = f2bf(san(v1.x)); o1.y = f2bf(san(v1.y)); o1.z = f2bf(san(v1.z)); o1.w = f2bf(san(v1.w));
      }
      *(us4*)&Af[r][c]     = o0;
      *(us4*)&Af[r][c + 4] = o1;
    }
    __syncthreads();
    #pragma unroll
    for (int kc = 0; kc < 128; kc += 32){
      s16x8 afr[4], bfr[2];
      #pragma unroll
      for (int mi = 0; mi < 4; mi++)
        afr[mi] = *(const s16x8*)(Ttw + (size_t)(m0 + 16*mi + l15)*256 + half*128 + kc + 8*q);
      #pragma unroll
      for (int ni = 0; ni < 2; ni++) bfr[ni] = *(const s16x8*)&Af[n0 + 16*ni + l15][kc + 8*q];
      #pragma unroll
      for (int mi = 0; mi < 4; mi++)
        #pragma unroll
        for (int ni = 0; ni < 2; ni++)
          acc[mi][ni] = __builtin_amdgcn_mfma_f32_16x16x32_bf16(afr[mi], bfr[ni], acc[mi][ni], 0, 0, 0);
    }
  }

  float bias[4][4];
  #pragma unroll
  for (int mi = 0; mi < 4; mi++){
    int c0 = m0 + 16*mi + 4*q;
    f32x4 bv = *(const f32x4*)(tb + c0);
    bias[mi][0] = san(bv.x); bias[mi][1] = san(bv.y); bias[mi][2] = san(bv.z); bias[mi][3] = san(bv.w);
  }
  #pragma unroll
  for (int ni = 0; ni < 2; ni++){
    float ss = 0.f;
    #pragma unroll
    for (int mi = 0; mi < 4; mi++){
      float v0 = acc[mi][ni].x + bias[mi][0];
      float v1 = acc[mi][ni].y + bias[mi][1];
      float v2 = acc[mi][ni].z + bias[mi][2];
      float v3 = acc[mi][ni].w + bias[mi][3];
      ss += v0*v0 + v1*v1 + v2*v2 + v3*v3;
    }
    rowss[n0 + 16*ni + l15][(w & 1)*4 + q] = ss;
  }
  __syncthreads();
  if (t < 64){
    float s = 0.f;
    #pragma unroll
    for (int j = 0; j < 8; j++) s += rowss[t][j];
    rnorm[t] = 1.0f / fmaxf(sqrtf(s), 1e-12f);
  }
  __syncthreads();
  #pragma unroll
  for (int mi = 0; mi < 4; mi++){
    int c0 = m0 + 16*mi + 4*q;
    #pragma unroll
    for (int ni = 0; ni < 2; ni++){
      int r = n0 + 16*ni + l15;
      int row = r0 + r;
      if (row < NI){
        float inv = rnorm[r];
        us4 o;
        o.x = f2bf((acc[mi][ni].x + bias[mi][0]) * inv);
        o.y = f2bf((acc[mi][ni].y + bias[mi][1]) * inv);
        o.z = f2bf((acc[mi][ni].z + bias[mi][2]) * inv);
        o.w = f2bf((acc[mi][ni].w + bias[mi][3]) * inv);
        *(us4*)(X + (size_t)(NU + row)*128 + c0) = o;
      }
    }
  }
}

// ---------------------------------------------------------------------------
// CSR build — LDS-sliced histogram, no global atomics.
// ---------------------------------------------------------------------------
__global__ __launch_bounds__(1024) void hist_lds(
    const int* __restrict__ dst, u32* __restrict__ countsC)
{
  __shared__ u32 cnt[HSW];
  int b = blockIdx.x;
  int s = b / HCHUNK, c = b % HCHUNK;
  int t = threadIdx.x;
  for (int i = t; i < HSW; i += 1024) cnt[i] = 0;
  __syncthreads();
  int lo = s * HSW;
  int hi = min(lo + HSW, NN);
  int e0 = c * HEPC, e1 = e0 + HEPC;
  for (int e = e0 + t*4; e < e1; e += 4096){
    int4 d4 = *(const int4*)(dst + e);
    int d0 = min(max(d4.x, 0), NN-1);
    int d1 = min(max(d4.y, 0), NN-1);
    int d2 = min(max(d4.z, 0), NN-1);
    int d3 = min(max(d4.w, 0), NN-1);
    if (d0 >= lo && d0 < hi) atomicAdd(&cnt[d0 - lo], 1u);
    if (d1 >= lo && d1 < hi) atomicAdd(&cnt[d1 - lo], 1u);
    if (d2 >= lo && d2 < hi) atomicAdd(&cnt[d2 - lo], 1u);
    if (d3 >= lo && d3 < hi) atomicAdd(&cnt[d3 - lo], 1u);
  }
  __syncthreads();
  u32* outp = countsC + (size_t)c*NN + lo;
  int w = hi - lo;
  for (int i = t; i < w; i += 1024) outp[i] = cnt[i];
}

__global__ __launch_bounds__(256) void reduce_counts(
    const u32* __restrict__ countsC, int* __restrict__ counts)
{
  int v = blockIdx.x*256 + threadIdx.x;
  if (v < NN){
    u32 sum = 0;
    #pragma unroll
    for (int c = 0; c < HCHUNK; c++) sum += countsC[(size_t)c*NN + v];
    counts[v] = (int)sum;
  }
}

// ---------------------------------------------------------------------------
// Multi-block scan (replaces the single-block scan_k: 800 KB through one CU
// plus 25 serialized chunk round-trips was ~20-40 us; this is ~5 us).
// p1: per-block inclusive scan of 4096 elems -> row_ptr (local) + bsum.
// p2: 1 small block scans the 25 block sums into exclusive carries.
// p3: add carry[b] to each block's row_ptr range.
// ---------------------------------------------------------------------------
__global__ __launch_bounds__(1024) void scan_p1(
    const int* __restrict__ counts, int* __restrict__ row_ptr, int* __restrict__ bsum)
{
  __shared__ int wsum[16];
  __shared__ int woff[16];
  int t = threadIdx.x;
  int lane = t & 63, wid = t >> 6;
  int idx = blockIdx.x*4096 + t*4;
  int4 v = {0,0,0,0};
  if (idx < NN) v = *(const int4*)(counts + idx);
  int s4 = v.x + v.y + v.z + v.w;
  int s = s4;
  #pragma unroll
  for (int off = 1; off < 64; off <<= 1){
    int u = __shfl_up(s, off, 64);
    if (lane >= off) s += u;
  }
  if (lane == 63) wsum[wid] = s;
  __syncthreads();
  if (t < 16){
    int ws = wsum[t];
    int wscan = ws;
    #pragma unroll
    for (int off = 1; off < 16; off <<= 1){
      int u = __shfl_up(wscan, off, 64);
      if (t >= off) wscan += u;
    }
    woff[t] = wscan - ws;
    if (t == 15) bsum[blockIdx.x] = wscan;   // block total
  }
  __syncthreads();
  if (idx < NN){
    int e0 = woff[wid] + (s - s4);
    int4 o;
    o.x = e0; o.y = e0 + v.x; o.z = o.y + v.y; o.w = o.z + v.z;
    *(int4*)(row_ptr + idx) = o;
  }
}

__global__ __launch_bounds__(64) void scan_p2(int* __restrict__ bsum, int nb)
{
  int t = threadIdx.x;
  int v = (t < nb) ? bsum[t] : 0;
  int s = v;
  #pragma unroll
  for (int off = 1; off < 64; off <<= 1){
    int u = __shfl_up(s, off, 64);
    if (t >= off) s += u;
  }
  if (t < nb) bsum[t] = s - v;   // exclusive carry
}

__global__ __launch_bounds__(1024) void scan_p3(
    int* __restrict__ row_ptr, const int* __restrict__ bsum)
{
  int c = bsum[blockIdx.x];
  if (c == 0) return;            // block 0 (and empty prefixes) skip
  int idx = blockIdx.x*4096 + threadIdx.x*4;
  if (idx < NN){
    int4 o = *(int4*)(row_ptr + idx);
    o.x += c; o.y += c; o.z += c; o.w += c;
    *(int4*)(row_ptr + idx) = o;
  }
}

// Sliced fill: pass p handles dst in [d0,d1); esrc window (~3.2 MB at
// NSLICE=2) stays L2-resident so the random 4B scatter doesn't write-allocate
// a 64B HBM line per edge. row_ptr doubles as cursor (post-fill it holds the
// shifted prefix: row_ptr[v] == original row_ptr[v+1]).
__global__ __launch_bounds__(256) void fill_slice(
    const int* __restrict__ src, const int* __restrict__ dst,
    int* __restrict__ row_ptr, int* __restrict__ esrc, int d0, int d1)
{
  int e = blockIdx.x*256 + threadIdx.x;
  if (e < NE){
    int d = dst[e];
    if (d >= d0 && d < d1){
      d = min(max(d, 0), NN - 1);
      int pos = atomicAdd(&row_ptr[d], 1);
      pos = min(max(pos, 0), NE - 1);
      esrc[pos] = src[e];
    }
  }
}

// ---------------------------------------------------------------------------
// Aggregation: one wave per node; quarter-wave (16 lanes x 16B) per edge,
// up to 16 edges in flight per wave; shuffle-reduce across sub-groups.
// (Standalone — the r7 in-layer fusion measured 210 us/dispatch with 188 MB
// FETCH: fused gather at 2 blocks/CU wrecks L2 locality. Keep separate.)
// ---------------------------------------------------------------------------
#define ACC8(P) \
  a0 += bf2f((u16)(P.x & 0xFFFF)); a1 += bf2f((u16)(P.x >> 16)); \
  a2 += bf2f((u16)(P.y & 0xFFFF)); a3 += bf2f((u16)(P.y >> 16)); \
  a4 += bf2f((u16)(P.z & 0xFFFF)); a5 += bf2f((u16)(P.z >> 16)); \
  a6 += bf2f((u16)(P.w & 0xFFFF)); a7 += bf2f((u16)(P.w >> 16));

__global__ __launch_bounds__(256) void aggregate(
    const u16* __restrict__ X, const int* __restrict__ row_ptr,
    const int* __restrict__ esrc, u16* __restrict__ AGG)
{
  int gid = blockIdx.x*256 + threadIdx.x;
  int v = gid >> 6, lane = gid & 63;
  int sub = lane >> 4, li = lane & 15;
  int jb = (v == 0) ? 0 : row_ptr[v - 1];
  int je = row_ptr[v];
  jb = min(max(jb, 0), NE);
  je = min(max(je, jb), NE);

  float a0=0.f,a1=0.f,a2=0.f,a3=0.f,a4=0.f,a5=0.f,a6=0.f,a7=0.f;

  int j = jb + sub;
  for (; j + 12 < je; j += 16){
    int s0 = esrc[j];      s0 = min(max(s0, 0), NN - 1);
    int s1 = esrc[j + 4];  s1 = min(max(s1, 0), NN - 1);
    int s2 = esrc[j + 8];  s2 = min(max(s2, 0), NN - 1);
    int s3 = esrc[j + 12]; s3 = min(max(s3, 0), NN - 1);
    uint4 p0 = *(const uint4*)(X + (size_t)s0*128 + li*8);
    uint4 p1 = *(const uint4*)(X + (size_t)s1*128 + li*8);
    uint4 p2 = *(const uint4*)(X + (size_t)s2*128 + li*8);
    uint4 p3 = *(const uint4*)(X + (size_t)s3*128 + li*8);
    ACC8(p0); ACC8(p1); ACC8(p2); ACC8(p3);
  }
  for (; j + 4 < je; j += 8){
    int s0 = esrc[j];     s0 = min(max(s0, 0), NN - 1);
    int s1 = esrc[j + 4]; s1 = min(max(s1, 0), NN - 1);
    uint4 p0 = *(const uint4*)(X + (size_t)s0*128 + li*8);
    uint4 p1 = *(const uint4*)(X + (size_t)s1*128 + li*8);
    ACC8(p0); ACC8(p1);
  }
  for (; j < je; j += 4){
    int s0 = esrc[j]; s0 = min(max(s0, 0), NN - 1);
    uint4 p0 = *(const uint4*)(X + (size_t)s0*128 + li*8);
    ACC8(p0);
  }

  a0 += __shfl_xor(a0, 16, 64); a0 += __shfl_xor(a0, 32, 64);
  a1 += __shfl_xor(a1, 16, 64); a1 += __shfl_xor(a1, 32, 64);
  a2 += __shfl_xor(a2, 16, 64); a2 += __shfl_xor(a2, 32, 64);
  a3 += __shfl_xor(a3, 16, 64); a3 += __shfl_xor(a3, 32, 64);
  a4 += __shfl_xor(a4, 16, 64); a4 += __shfl_xor(a4, 32, 64);
  a5 += __shfl_xor(a5, 16, 64); a5 += __shfl_xor(a5, 32, 64);
  a6 += __shfl_xor(a6, 16, 64); a6 += __shfl_xor(a6, 32, 64);
  a7 += __shfl_xor(a7, 16, 64); a7 += __shfl_xor(a7, 32, 64);

  if (sub == 0){
    uint4 o;
    o.x = pack2(a0, a1); o.y = pack2(a2, a3);
    o.z = pack2(a4, a5); o.w = pack2(a6, a7);
    *(uint4*)(AGG + (size_t)v*128 + li*8) = o;
  }
}

// ---------------------------------------------------------------------------
// Fused dense layer — round-0 structure (measured best: 59 us with bf16 nemb).
// 4 waves, 64x64 output sub-tiles, weight A-fragments loaded in-phase from
// global (L2-hot). Geometry variants all regressed: 64-row tile (r1, +8),
// register cross-phase prefetch (r2-r4, +8), 8-wave split (r6, +10),
// fused gather (r7, +130).
// ---------------------------------------------------------------------------
__global__ __launch_bounds__(256, 2) void layer_fused(
    const u16* __restrict__ AGG, const u16* __restrict__ nembB,
    const u16* __restrict__ Twi, const u16* __restrict__ Tdi,
    const float* __restrict__ dbF, const u16* __restrict__ Toi,
    const float* __restrict__ obF, u16* __restrict__ XoutB,
    float* __restrict__ XoutF, int last)
{
  __shared__ __align__(16) u16 Ab[128][136];   // agg (stage1 B), then u (stage3b B)
  __shared__ __align__(16) u16 Hb[128][136];   // h   (stage2/3a B)

  int t = threadIdx.x;
  int r0 = blockIdx.x * 128;
  int w = t >> 6, lane = t & 63;
  int l15 = lane & 15, q = lane >> 4;
  int m0 = (w & 1) * 64, n0 = (w >> 1) * 64;

  f32x4 acc[4][4];

#define ZERO_ACC() \
  { _Pragma("unroll") for (int mi = 0; mi < 4; mi++) \
      { _Pragma("unroll") for (int ni = 0; ni < 4; ni++) \
        { acc[mi][ni].x = 0.f; acc[mi][ni].y = 0.f; acc[mi][ni].z = 0.f; acc[mi][ni].w = 0.f; } } }

#define GEMMG(BARR, WBASE, WSTRIDE, WKOFF) \
  { s16x8 afr[4][4]; \
    _Pragma("unroll") for (int mi = 0; mi < 4; mi++) \
      { _Pragma("unroll") for (int kk = 0; kk < 4; kk++) \
          afr[mi][kk] = *(const s16x8*)((WBASE) + (size_t)(m0 + 16*mi + l15)*(WSTRIDE) + (WKOFF) + kk*32 + 8*q); } \
    _Pragma("unroll") for (int kk = 0; kk < 4; kk++){ \
      s16x8 bfr[4]; \
      _Pragma("unroll") for (int ni = 0; ni < 4; ni++) bfr[ni] = *(const s16x8*)&BARR[n0 + 16*ni + l15][kk*32 + 8*q]; \
      _Pragma("unroll") for (int mi = 0; mi < 4; mi++) \
        { _Pragma("unroll") for (int ni = 0; ni < 4; ni++) \
          acc[mi][ni] = __builtin_amdgcn_mfma_f32_16x16x32_bf16(afr[mi][kk], bfr[ni], acc[mi][ni], 0, 0, 0); } } }

  // stage agg tile into Ab
  #pragma unroll
  for (int p = 0; p < 8; p++){
    int fi = (p*256 + t)*8;
    int r = fi >> 7, c = fi & 127;
    int row = r0 + r;
    us4 o0 = {0,0,0,0}, o1 = {0,0,0,0};
    if (row < NN){
      o0 = *(const us4*)(AGG + (size_t)row*128 + c);
      o1 = *(const us4*)(AGG + (size_t)row*128 + c + 4);
    }
    *(us4*)&Ab[r][c]     = o0;
    *(us4*)&Ab[r][c + 4] = o1;
  }
  __syncthreads();

  // stage 1: H^T = Tw * Agg^T
  ZERO_ACC();
  GEMMG(Ab, Twi, 128, 0);

  // write h (lrelu) into Hb
  #pragma unroll
  for (int mi = 0; mi < 4; mi++){
    #pragma unroll
    for (int ni = 0; ni < 4; ni++){
      us4 o;
      o.x = f2bf(lrelu(acc[mi][ni].x));
      o.y = f2bf(lrelu(acc[mi][ni].y));
      o.z = f2bf(lrelu(acc[mi][ni].z));
      o.w = f2bf(lrelu(acc[mi][ni].w));
      *(us4*)&Hb[n0 + 16*ni + l15][m0 + 16*mi + 4*q] = o;
    }
  }
  __syncthreads();   // Hb complete; also guarantees all stage-1 reads of Ab done

  // stage 2: U^T = Td * H^T
  ZERO_ACC();
  GEMMG(Hb, Tdi, 128, 0);

  // write u = lrelu(. + des_b + node_emb) into Ab
  #pragma unroll
  for (int mi = 0; mi < 4; mi++){
    int c0 = m0 + 16*mi + 4*q;
    f32x4 dbv = *(const f32x4*)(dbF + c0);
    float db0 = san(dbv.x), db1 = san(dbv.y), db2 = san(dbv.z), db3 = san(dbv.w);
    #pragma unroll
    for (int ni = 0; ni < 4; ni++){
      int r = n0 + 16*ni + l15;
      int row = r0 + r;
      float e0 = 0.f, e1 = 0.f, e2 = 0.f, e3 = 0.f;
      if (row < NN){
        us4 ne = *(const us4*)(nembB + (size_t)row*128 + c0);
        e0 = bf2f(ne.x); e1 = bf2f(ne.y); e2 = bf2f(ne.z); e3 = bf2f(ne.w);
      }
      us4 o;
      o.x = f2bf(lrelu(acc[mi][ni].x + db0 + e0));
      o.y = f2bf(lrelu(acc[mi][ni].y + db1 + e1));
      o.z = f2bf(lrelu(acc[mi][ni].z + db2 + e2));
      o.w = f2bf(lrelu(acc[mi][ni].w + db3 + e3));
      *(us4*)&Ab[r][c0] = o;
    }
  }
  __syncthreads();   // u complete

  // stage 3: X^T = To[:,0:128]*H^T + To[:,128:256]*U^T
  ZERO_ACC();
  GEMMG(Hb, Toi, 256, 0);
  GEMMG(Ab, Toi, 256, 128);

  #pragma unroll
  for (int mi = 0; mi < 4; mi++){
    int c0 = m0 + 16*mi + 4*q;
    f32x4 obv = *(const f32x4*)(obF + c0);
    float b0 = san(obv.x), b1 = san(obv.y), b2 = san(obv.z), b3 = san(obv.w);
    #pragma unroll
    for (int ni = 0; ni < 4; ni++){
      int r = n0 + 16*ni + l15;
      int row = r0 + r;
      if (row < NN){
        if (last){
          f32x4 o;
          o.x = lrelu(acc[mi][ni].x + b0);
          o.y = lrelu(acc[mi][ni].y + b1);
          o.z = lrelu(acc[mi][ni].z + b2);
          o.w = lrelu(acc[mi][ni].w + b3);
          *(f32x4*)(XoutF + (size_t)row*128 + c0) = o;
        } else {
          us4 o;
          o.x = f2bf(lrelu(acc[mi][ni].x + b0));
          o.y = f2bf(lrelu(acc[mi][ni].y + b1));
          o.z = f2bf(lrelu(acc[mi][ni].z + b2));
          o.w = f2bf(lrelu(acc[mi][ni].w + b3));
          *(us4*)(XoutB + (size_t)row*128 + c0) = o;
        }
      }
    }
  }
#undef ZERO_ACC
#undef GEMMG
}

// ---------------------------------------------------------------------------
__global__ void copy_ufe(const float4* __restrict__ s, float4* __restrict__ d, int n){
  int i = blockIdx.x*256 + threadIdx.x;
  if (i < n){
    float4 v = s[i];
    v.x = san(v.x); v.y = san(v.y); v.z = san(v.z); v.w = san(v.w);
    d[i] = v;
  }
}

// ---------------------------------------------------------------------------
extern "C" void kernel_launch(void* const* d_in, const int* in_sizes, int n_in,
                              void* d_out, int out_size, void* d_ws, size_t ws_size,
                              hipStream_t stream)
{
  const float* feat = (const float*)d_in[0];
  const float* nemb = (const float*)d_in[1];
  const int*   src  = (const int*)d_in[2];
  const int*   dst  = (const int*)d_in[3];
  const float* ufe  = (const float*)d_in[4];
  const float* tw   = (const float*)d_in[5];
  const float* tb   = (const float*)d_in[6];
  const float* wsw  = (const float*)d_in[7];
  const float* desw = (const float*)d_in[8];
  const float* desb = (const float*)d_in[9];
  const float* outw = (const float*)d_in[10];
  const float* outb = (const float*)d_in[11];

  float* out  = (float*)d_out;
  float* outU = out + (size_t)NN*128;

  // bf16 X table aliases the first 25.6 MB of d_out; layer 2 overwrites the
  // full region with the fp32 result after its aggregate consumed X.
  u16* X = (u16*)out;
  // bf16 node_emb lives in the outU tail (25.6 MB); copy_ufe overwrites it
  // at the very end.
  u16* nembB = (u16*)outU;

  char* p = (char*)d_ws;
  u16*   AGG = (u16*)p;    p += (size_t)NN*128*2;
  u16*   Ttw = (u16*)p;    p += (size_t)2*16384*2;
  u16*   Tw  = (u16*)p;    p += (size_t)3*16384*2;
  u16*   Td  = (u16*)p;    p += (size_t)3*16384*2;
  u16*   To  = (u16*)p;    p += (size_t)3*32768*2;
  int* row_ptr = (int*)p;  p += (size_t)100004*4;
  int* counts  = (int*)p;  p += (size_t)100000*4;
  int* bsum    = (int*)p;  p += (size_t)64*4;
  int* esrc    = (int*)p;  p += (size_t)NE*4;
  // countsC (HCHUNK*NN u32 = 25.6 MB) aliases AGG: dead after reduce_counts,
  // long before aggregate first writes AGG.
  u32* countsC = (u32*)AGG;

  prep<<<PREP_TW + PREP_CONV + PREP_NORM, 256, 0, stream>>>(
      tw, wsw, desw, outw, Ttw, Tw, Td, To, nemb, nembB, ufe, X);
  trans_items<<<(NI + 63)/64, 256, 0, stream>>>(feat, Ttw, tb, X);

  hist_lds<<<HSLICE*HCHUNK, 1024, 0, stream>>>(dst, countsC);
  reduce_counts<<<(NN + 255)/256, 256, 0, stream>>>(countsC, counts);
  int nsb = (NN + 4095)/4096;   // 25
  scan_p1<<<nsb, 1024, 0, stream>>>(counts, row_ptr, bsum);
  scan_p2<<<1, 64, 0, stream>>>(bsum, nsb);
  scan_p3<<<nsb, 1024, 0, stream>>>(row_ptr, bsum);
  for (int s = 0; s < NSLICE; s++){
    fill_slice<<<(NE + 255)/256, 256, 0, stream>>>(src, dst, row_ptr, esrc,
        s*SLICEW, (s == NSLICE-1) ? NN : (s+1)*SLICEW);
  }

  for (int i = 0; i < 3; i++){
    aggregate<<<NN/4, 256, 0, stream>>>(X, row_ptr, esrc, AGG);
    layer_fused<<<(NN + 127)/128, 256, 0, stream>>>(AGG, nembB,
        Tw + (size_t)i*16384, Td + (size_t)i*16384, desb + (size_t)i*128,
        To + (size_t)i*32768, outb + (size_t)i*128, X, out, (i == 2) ? 1 : 0);
  }
  copy_ufe<<<(NU*128/4 + 255)/256, 256, 0, stream>>>((const float4*)ufe, (float4*)outU, NU*128/4);
}